// Round 2
// baseline (426.098 us; speedup 1.0000x reference)
//
#include <hip/hip_runtime.h>

typedef unsigned short u16;
typedef unsigned int u32;
typedef __attribute__((ext_vector_type(8))) short short8;
typedef __attribute__((ext_vector_type(4))) float f32x4;

__device__ __forceinline__ float bf2f(u16 u){ union { u32 i; float f; } x; x.i = ((u32)u)<<16; return x.f; }
__device__ __forceinline__ u16 f2bf(float f){ union { float f; u32 i; } x; x.f = f; u32 r = x.i + 0x7fffu + ((x.i>>16)&1u); return (u16)(r>>16); }

#define MFMA16(a,b,c) __builtin_amdgcn_mfma_f32_16x16x32_bf16((a),(b),(c),0,0,0)

// ---- dual-dtype external loads: fp32 inputs are converted to bf16 at ingest ----
__device__ __forceinline__ uint4 ld8(const void* p, size_t off, int f32) {
  if (f32) {
    const float* fp = (const float*)p + off;
    float4 a = *(const float4*)fp;
    float4 b = *(const float4*)(fp + 4);
    uint4 o;
    o.x = (u32)f2bf(a.x) | ((u32)f2bf(a.y)<<16);
    o.y = (u32)f2bf(a.z) | ((u32)f2bf(a.w)<<16);
    o.z = (u32)f2bf(b.x) | ((u32)f2bf(b.y)<<16);
    o.w = (u32)f2bf(b.z) | ((u32)f2bf(b.w)<<16);
    return o;
  }
  return *(const uint4*)((const u16*)p + off);
}
__device__ __forceinline__ uint2 ld4(const void* p, size_t off, int f32) {
  if (f32) {
    const float* fp = (const float*)p + off;
    float4 a = *(const float4*)fp;
    uint2 o;
    o.x = (u32)f2bf(a.x) | ((u32)f2bf(a.y)<<16);
    o.y = (u32)f2bf(a.z) | ((u32)f2bf(a.w)<<16);
    return o;
  }
  return *(const uint2*)((const u16*)p + off);
}
__device__ __forceinline__ float ldsc(const void* p, size_t off, int f32) {
  if (f32) return ((const float*)p)[off];
  return bf2f(((const u16*)p)[off]);
}

// ---- K-1: detect input dtype from x's low 16 bits (bf16 exponent vs fp32 mantissa) ----
__global__ __launch_bounds__(256) void k_detect(const u32* __restrict__ x, int* __restrict__ flag)
{
  __shared__ int cnt;
  if (threadIdx.x == 0) cnt = 0;
  __syncthreads();
  int c = 0;
  #pragma unroll
  for (int i = 0; i < 32; ++i) {
    u32 w = x[threadIdx.x*32 + i];
    u32 e = (w >> 7) & 0xFFu;             // low-half bf16 exponent field
    c += (e == 0u || (e >= 96u && e <= 143u)) ? 1 : 0;
  }
  atomicAdd(&cnt, c);
  __syncthreads();
  if (threadIdx.x == 0) *flag = (cnt < 4915) ? 1 : 0;   // bf16 ~8192, fp32 ~1570
}

// ---------------- K0: transpose x (B,C,HW) -> xt (B*HW, C), bf16 ----------------
__global__ __launch_bounds__(256) void k_transpose(const void* __restrict__ x, u16* __restrict__ xt,
                                                   const int* __restrict__ flagp)
{
  __shared__ int sflag;
  __shared__ __align__(16) u16 tile[64][68];
  if (threadIdx.x == 0) sflag = *flagp;
  __syncthreads();
  const int f32 = sflag;
  const int p0 = blockIdx.x*64, c0 = blockIdx.y*64, b = blockIdx.z;
  const int t = threadIdx.x;
  const size_t xbo = ((size_t)(b*256 + c0))*4096 + p0;
  #pragma unroll
  for (int pass=0; pass<4; ++pass) {
    int cl = pass*16 + (t>>4);
    int pl = (t&15)*4;
    uint2 v = ld4(x, xbo + (size_t)cl*4096 + pl, f32);
    *(uint2*)&tile[cl][pl] = v;
  }
  __syncthreads();
  u16* xtb = xt + ((size_t)b*4096 + p0)*256 + c0;
  #pragma unroll
  for (int pass=0; pass<4; ++pass) {
    int pl = pass*16 + (t>>4);
    int cl = (t&15)*4;
    unsigned int lo = (unsigned int)tile[cl][pl]   | ((unsigned int)tile[cl+1][pl]<<16);
    unsigned int hi = (unsigned int)tile[cl+2][pl] | ((unsigned int)tile[cl+3][pl]<<16);
    uint2 o; o.x = lo; o.y = hi;
    *(uint2*)(xtb + (size_t)pl*256 + cl) = o;
  }
}

// ------------- generic GEMM: C[M,N] = A[M,K] @ Bt[N,K]^T * scale + bias --------------
// A is always an internal bf16 arena; Bt/bias are external (dual-dtype).
// shuffle=1: scatter as PixelShuffle(2) into d_out (dual-dtype store).
__global__ __launch_bounds__(256) void k_gemm_bt(
  const u16* __restrict__ A, const void* __restrict__ Bt, const void* __restrict__ bias,
  void* __restrict__ C, int M, int N, int K, float scale, int shuffle,
  const int* __restrict__ flagp)
{
  __shared__ int sflag;
  __shared__ __align__(16) u16 Als[128*32];
  __shared__ __align__(16) u16 Bls[128*32];
  if (threadIdx.x == 0) sflag = *flagp;
  __syncthreads();
  const int f32 = sflag;
  const int m0 = blockIdx.x*128, n0 = blockIdx.y*128;
  const int t = threadIdx.x, lane = t & 63, wv = t >> 6;
  const int wm = (wv & 1)*64, wn = (wv >> 1)*64;
  const int lm = lane & 15, lq = lane >> 4;
  f32x4 acc[4][4] = {};
  for (int k0 = 0; k0 < K; k0 += 32) {
    #pragma unroll
    for (int i = 0; i < 2; ++i) {
      int u = t + i*256;
      int row = u >> 2, ch = (u & 3)*8;
      *(uint4*)&Als[row*32 + ch] = *(const uint4*)(A + (size_t)(m0+row)*K + k0 + ch);
      *(uint4*)&Bls[row*32 + ch] = ld8(Bt, (size_t)(n0+row)*K + k0 + ch, f32);
    }
    __syncthreads();
    short8 af[4], bf[4];
    #pragma unroll
    for (int i=0;i<4;++i) af[i] = *(const short8*)&Als[(wm + i*16 + lm)*32 + lq*8];
    #pragma unroll
    for (int i=0;i<4;++i) bf[i] = *(const short8*)&Bls[(wn + i*16 + lm)*32 + lq*8];
    #pragma unroll
    for (int mt=0;mt<4;++mt)
      #pragma unroll
      for (int nt=0;nt<4;++nt)
        acc[mt][nt] = MFMA16(af[mt], bf[nt], acc[mt][nt]);
    __syncthreads();
  }
  #pragma unroll
  for (int nt=0;nt<4;++nt) {
    int col = n0 + wn + nt*16 + lm;
    float bv = bias ? ldsc(bias, col, f32) : 0.0f;
    #pragma unroll
    for (int mt=0;mt<4;++mt) {
      #pragma unroll
      for (int r=0;r<4;++r) {
        int row = m0 + wm + mt*16 + lq*4 + r;
        float v = acc[mt][nt][r]*scale + bv;
        if (!shuffle) {
          ((u16*)C)[(size_t)row*N + col] = f2bf(v);
        } else {
          int b = row >> 12, hw = row & 4095;
          int hh = hw >> 6, ww = hw & 63;
          int cn = col >> 2, rr = (col >> 1) & 1, ss = col & 1;
          size_t idx = ((((size_t)(b*256 + cn))*128 + hh*2 + rr) << 7) + (size_t)(ww*2 + ss);
          if (f32) ((float*)C)[idx] = v;
          else     ((u16*)C)[idx]   = f2bf(v);
        }
      }
    }
  }
}

// ---------------- K2: halo attention, one WG per (block, head) ----------------
#define MASKVAL (-30000.0f)
__global__ __launch_bounds__(256) void k_halo_attn(
  const u16* __restrict__ qo, const u16* __restrict__ kv,
  const void* __restrict__ relh, const void* __restrict__ relw,
  u16* __restrict__ aout, const int* __restrict__ flagp)
{
  __shared__ int sflag;
  __shared__ __align__(16) u16 Qs[64*72];    // Q  [64][72]
  __shared__ __align__(16) u16 KP[128*72];   // K tile; reused: rel tables, then P [64][136]
  __shared__ __align__(16) u16 Vt[64*136];   // V^T tile [64 d][136 keys-padded]
  __shared__ __align__(16) u16 Gw[64*32];    // rel-w logits gather table (bf16)
  __shared__ __align__(16) u16 Gh[64*32];
  if (threadIdx.x == 0) sflag = *flagp;
  __syncthreads();
  const int f32 = sflag;

  const int blk = blockIdx.x, head = blockIdx.y;
  const int bb = blk >> 6, by = (blk >> 3) & 7, bx = blk & 7;
  const int h0 = by*8, w0 = bx*8;
  const int t = threadIdx.x, lane = t & 63, wv = t >> 6;
  const int lm = lane & 15, lq = lane >> 4;
  const size_t pixbase = (size_t)bb * 4096;
  const float LOG2E = 1.4426950408889634f;

  // stage Q (scaled q, 64 rows x 64 d)
  #pragma unroll
  for (int i=0;i<2;++i) {
    int u = t + i*256;
    int row = u >> 3, ch = (u & 7)*8;
    int qx = row >> 3, qy = row & 7;
    size_t p = pixbase + (size_t)(h0+qx)*64 + (w0+qy);
    *(uint4*)&Qs[row*72 + ch] = *(const uint4*)(qo + p*256 + head*64 + ch);
  }
  // stage rel tables (31x64, pad row 31 = 0) into KP region
  {
    u16* RW = KP; u16* RH = KP + 2048;
    if (t < 248) {
      *(uint4*)&RW[t*8] = ld8(relw, (size_t)t*8, f32);
      *(uint4*)&RH[t*8] = ld8(relh, (size_t)t*8, f32);
    } else {
      uint4 z; z.x=z.y=z.z=z.w=0;
      int o = 1984 + (t-248)*8;
      *(uint4*)&RW[o] = z;
      *(uint4*)&RH[o] = z;
    }
  }
  __syncthreads();
  // G = Q @ rel^T (this wave's 16 q-rows, 31 real cols) -> LDS bf16
  {
    const u16* RW = KP; const u16* RH = KP + 2048;
    f32x4 agw[2] = {}, agh[2] = {};
    #pragma unroll
    for (int ks=0;ks<2;++ks) {
      short8 aq = *(const short8*)&Qs[(wv*16 + lm)*72 + ks*32 + lq*8];
      #pragma unroll
      for (int nt=0;nt<2;++nt) {
        short8 bw = *(const short8*)&RW[(nt*16 + lm)*64 + ks*32 + lq*8];
        short8 bh = *(const short8*)&RH[(nt*16 + lm)*64 + ks*32 + lq*8];
        agw[nt] = MFMA16(aq, bw, agw[nt]);
        agh[nt] = MFMA16(aq, bh, agh[nt]);
      }
    }
    #pragma unroll
    for (int nt=0;nt<2;++nt)
      #pragma unroll
      for (int r=0;r<4;++r) {
        int m = wv*16 + lq*4 + r, c = nt*16 + lm;
        Gw[m*32 + c] = f2bf(agw[nt][r]);
        Gh[m*32 + c] = f2bf(agh[nt][r]);
      }
  }
  __syncthreads();   // rel reads done before K staging overwrites KP

  float m_run[4], l_run[4];
  #pragma unroll
  for (int r=0;r<4;++r){ m_run[r] = MASKVAL; l_run[r] = 0.0f; }
  f32x4 acc_o[4] = {};

  for (int tile=0; tile<2; ++tile) {
    // stage K tile (128 keys x 64 d), zero-filled outside the image
    #pragma unroll
    for (int i=0;i<4;++i) {
      int u = t + i*256;
      int kl = u >> 3, ch = (u & 7)*8;
      int ki = tile*8 + (kl >> 4), kj = kl & 15;
      int hk = h0 - 4 + ki, wk = w0 - 4 + kj;
      uint4 v; v.x=v.y=v.z=v.w=0;
      if ((unsigned)hk < 64u && (unsigned)wk < 64u) {
        size_t p = pixbase + (size_t)hk*64 + wk;
        v = *(const uint4*)(kv + p*512 + head*64 + ch);
      }
      *(uint4*)&KP[kl*72 + ch] = v;
    }
    // stage V tile transposed: Vt[d][key]
    {
      int kl = t & 127, db = (t >> 7)*32;
      int ki = tile*8 + (kl >> 4), kj = kl & 15;
      int hk = h0 - 4 + ki, wk = w0 - 4 + kj;
      bool ok = ((unsigned)hk < 64u) && ((unsigned)wk < 64u);
      size_t p = pixbase + (size_t)hk*64 + wk;
      const u16* vp = kv + p*512 + 256 + head*64 + db;
      #pragma unroll
      for (int c=0;c<4;++c) {
        union { uint4 v; u16 s[8]; } uu;
        uu.v.x=uu.v.y=uu.v.z=uu.v.w=0;
        if (ok) uu.v = *(const uint4*)(vp + c*8);
        #pragma unroll
        for (int jj=0;jj<8;++jj) Vt[(db + c*8 + jj)*136 + kl] = uu.s[jj];
      }
    }
    __syncthreads();
    // sim: wave's 16 q-rows x 128 keys
    f32x4 as[8] = {};
    #pragma unroll
    for (int ks=0;ks<2;++ks) {
      short8 aq = *(const short8*)&Qs[(wv*16 + lm)*72 + ks*32 + lq*8];
      #pragma unroll
      for (int nt=0;nt<8;++nt) {
        short8 bk = *(const short8*)&KP[(nt*16 + lm)*72 + ks*32 + lq*8];
        as[nt] = MFMA16(aq, bk, as[nt]);
      }
    }
    __syncthreads();   // every wave done reading K before P overwrites KP
    // online softmax + write P (bf16) into KP as [64][136]
    #pragma unroll
    for (int r=0;r<4;++r) {
      int m = wv*16 + lq*4 + r;
      int qx = m >> 3, qy = m & 7;
      float vals[8]; float rowmax = MASKVAL;
      #pragma unroll
      for (int nt=0;nt<8;++nt) {
        int ki = tile*8 + nt;
        int hk = h0 - 4 + ki, wk = w0 - 4 + lm;
        float v = as[nt][r]
                + bf2f(Gw[m*32 + (lm - qy + 15)])
                + bf2f(Gh[m*32 + (ki - qx + 15)]);
        if (!((unsigned)hk < 64u && (unsigned)wk < 64u)) v = MASKVAL;
        vals[nt] = v;
        rowmax = fmaxf(rowmax, v);
      }
      #pragma unroll
      for (int s=1;s<16;s<<=1) rowmax = fmaxf(rowmax, __shfl_xor(rowmax, s, 64));
      float mnew = fmaxf(m_run[r], rowmax);
      float alpha = exp2f((m_run[r] - mnew)*LOG2E);
      float rs = 0.0f;
      #pragma unroll
      for (int nt=0;nt<8;++nt) {
        float e = exp2f((vals[nt] - mnew)*LOG2E);
        rs += e;
        KP[m*136 + nt*16 + lm] = f2bf(e);
      }
      #pragma unroll
      for (int s=1;s<16;s<<=1) rs += __shfl_xor(rs, s, 64);
      l_run[r] = l_run[r]*alpha + rs;
      m_run[r] = mnew;
      #pragma unroll
      for (int nt=0;nt<4;++nt) acc_o[nt][r] *= alpha;
    }
    __syncthreads();   // P complete
    // O += P @ V
    #pragma unroll
    for (int ks=0;ks<4;++ks) {
      short8 ap = *(const short8*)&KP[(wv*16 + lm)*136 + ks*32 + lq*8];
      #pragma unroll
      for (int nt=0;nt<4;++nt) {
        short8 bv = *(const short8*)&Vt[(nt*16 + lm)*136 + ks*32 + lq*8];
        acc_o[nt] = MFMA16(ap, bv, acc_o[nt]);
      }
    }
    __syncthreads();   // P/V reads done before next tile staging
  }
  // epilogue: normalize and store (pixel-major, col = head*64+dd)
  #pragma unroll
  for (int nt=0;nt<4;++nt)
    #pragma unroll
    for (int r=0;r<4;++r) {
      int m = wv*16 + lq*4 + r;
      int qx = m >> 3, qy = m & 7;
      size_t p = pixbase + (size_t)(h0+qx)*64 + (w0+qy);
      aout[p*256 + head*64 + nt*16 + lm] = f2bf(acc_o[nt][r]/l_run[r]);
    }
}

extern "C" void kernel_launch(void* const* d_in, const int* in_sizes, int n_in,
                              void* d_out, int out_size, void* d_ws, size_t ws_size,
                              hipStream_t stream)
{
  const void* x     = d_in[0];
  const void* wq    = d_in[1];
  const void* wkv   = d_in[2];
  const void* wo    = d_in[3];
  const void* bo    = d_in[4];
  const void* relh  = d_in[5];
  const void* relw  = d_in[6];
  const void* wconv = d_in[7];
  const void* bconv = d_in[8];

  // Arenas (bf16, element offsets within d_out's byte space — fits under
  // either output dtype). Lifetimes: xt dies after the projections; kv/qo die
  // after attention (aout runs in-place over qo: exactly one block reads and
  // then writes each (blk,head) region); y2 (ws) dies after the conv, which
  // overwrites all of d_out last.
  int* flag = (int*)d_ws;
  u16* y2   = (u16*)((char*)d_ws + 4096);     // 32768 x 256 (16 MiB)
  u16* base = (u16*)d_out;
  u16* kvb  = base;                            // 32768 x 512
  u16* qo   = base + 16777216;                 // 32768 x 256
  u16* xt   = base + 25165824;                 // 32768 x 256
  u16* aout = qo;                              // in-place

  k_detect<<<1, 256, 0, stream>>>((const u32*)x, flag);
  k_transpose<<<dim3(64,4,8), 256, 0, stream>>>(x, xt, flag);
  k_gemm_bt<<<dim3(256,2), 256, 0, stream>>>(xt, wq,  nullptr, qo,  32768, 256, 256, 0.125f, 0, flag);
  k_gemm_bt<<<dim3(256,4), 256, 0, stream>>>(xt, wkv, nullptr, kvb, 32768, 512, 256, 1.0f,   0, flag);
  k_halo_attn<<<dim3(512,4), 256, 0, stream>>>(qo, kvb, relh, relw, aout, flag);
  k_gemm_bt<<<dim3(256,2), 256, 0, stream>>>(aout, wo, bo, y2, 32768, 256, 256, 1.0f, 0, flag);
  k_gemm_bt<<<dim3(256,8), 256, 0, stream>>>(y2, wconv, bconv, d_out, 32768, 1024, 256, 1.0f, 1, flag);
}

// Round 3
// 406.444 us; speedup vs baseline: 1.0484x; 1.0484x over previous
//
#include <hip/hip_runtime.h>

typedef unsigned short u16;
typedef unsigned int u32;
typedef __attribute__((ext_vector_type(8))) short short8;
typedef __attribute__((ext_vector_type(4))) float f32x4;

__device__ __forceinline__ float bf2f(u16 u){ union { u32 i; float f; } x; x.i = ((u32)u)<<16; return x.f; }
__device__ __forceinline__ u16 f2bf(float f){ union { float f; u32 i; } x; x.f = f; u32 r = x.i + 0x7fffu + ((x.i>>16)&1u); return (u16)(r>>16); }

#define MFMA16(a,b,c) __builtin_amdgcn_mfma_f32_16x16x32_bf16((a),(b),(c),0,0,0)

// ---- dual-dtype external loads: fp32 inputs are converted to bf16 at ingest ----
__device__ __forceinline__ uint4 ld8(const void* p, size_t off, int f32) {
  if (f32) {
    const float* fp = (const float*)p + off;
    float4 a = *(const float4*)fp;
    float4 b = *(const float4*)(fp + 4);
    uint4 o;
    o.x = (u32)f2bf(a.x) | ((u32)f2bf(a.y)<<16);
    o.y = (u32)f2bf(a.z) | ((u32)f2bf(a.w)<<16);
    o.z = (u32)f2bf(b.x) | ((u32)f2bf(b.y)<<16);
    o.w = (u32)f2bf(b.z) | ((u32)f2bf(b.w)<<16);
    return o;
  }
  return *(const uint4*)((const u16*)p + off);
}
__device__ __forceinline__ uint2 ld4(const void* p, size_t off, int f32) {
  if (f32) {
    const float* fp = (const float*)p + off;
    float4 a = *(const float4*)fp;
    uint2 o;
    o.x = (u32)f2bf(a.x) | ((u32)f2bf(a.y)<<16);
    o.y = (u32)f2bf(a.z) | ((u32)f2bf(a.w)<<16);
    return o;
  }
  return *(const uint2*)((const u16*)p + off);
}
__device__ __forceinline__ float ldsc(const void* p, size_t off, int f32) {
  if (f32) return ((const float*)p)[off];
  return bf2f(((const u16*)p)[off]);
}

// ---- K-1: detect input dtype from x's low 16 bits (bf16 exponent vs fp32 mantissa) ----
__global__ __launch_bounds__(256) void k_detect(const u32* __restrict__ x, int* __restrict__ flag)
{
  __shared__ int cnt;
  if (threadIdx.x == 0) cnt = 0;
  __syncthreads();
  int c = 0;
  #pragma unroll
  for (int i = 0; i < 32; ++i) {
    u32 w = x[threadIdx.x*32 + i];
    u32 e = (w >> 7) & 0xFFu;             // low-half bf16 exponent field
    c += (e == 0u || (e >= 96u && e <= 143u)) ? 1 : 0;
  }
  atomicAdd(&cnt, c);
  __syncthreads();
  if (threadIdx.x == 0) *flag = (cnt < 4915) ? 1 : 0;   // bf16 ~8192, fp32 ~1570
}

// ---------------- K0: transpose x (B,C,HW) -> xt (B*HW, C), bf16 ----------------
__global__ __launch_bounds__(256) void k_transpose(const void* __restrict__ x, u16* __restrict__ xt,
                                                   const int* __restrict__ flagp)
{
  __shared__ int sflag;
  __shared__ __align__(16) u16 tile[64][68];
  if (threadIdx.x == 0) sflag = *flagp;
  __syncthreads();
  const int f32 = sflag;
  const int p0 = blockIdx.x*64, c0 = blockIdx.y*64, b = blockIdx.z;
  const int t = threadIdx.x;
  const size_t xbo = ((size_t)(b*256 + c0))*4096 + p0;
  #pragma unroll
  for (int pass=0; pass<4; ++pass) {
    int cl = pass*16 + (t>>4);
    int pl = (t&15)*4;
    uint2 v = ld4(x, xbo + (size_t)cl*4096 + pl, f32);
    *(uint2*)&tile[cl][pl] = v;
  }
  __syncthreads();
  u16* xtb = xt + ((size_t)b*4096 + p0)*256 + c0;
  #pragma unroll
  for (int pass=0; pass<4; ++pass) {
    int pl = pass*16 + (t>>4);
    int cl = (t&15)*4;
    unsigned int lo = (unsigned int)tile[cl][pl]   | ((unsigned int)tile[cl+1][pl]<<16);
    unsigned int hi = (unsigned int)tile[cl+2][pl] | ((unsigned int)tile[cl+3][pl]<<16);
    uint2 o; o.x = lo; o.y = hi;
    *(uint2*)(xtb + (size_t)pl*256 + cl) = o;
  }
}

// ------------- generic GEMM: C[M,N] = A[M,K] @ Bt[N,K]^T * scale + bias --------------
// A is always an internal bf16 arena; Bt/bias are external (dual-dtype).
// Epilogue goes through LDS so all global stores are wide & coalesced.
// shuffle=1: PixelShuffle(2) output (dual-dtype store), emits full 512B rows.
__global__ __launch_bounds__(256) void k_gemm_bt(
  const u16* __restrict__ A, const void* __restrict__ Bt, const void* __restrict__ bias,
  void* __restrict__ C, int M, int N, int K, float scale, int shuffle,
  const int* __restrict__ flagp)
{
  __shared__ int sflag;
  __shared__ __align__(16) char smem[20608];
  u16* Als = (u16*)smem;             // 128 x 40 (staging; stride 40 u16 = 80B -> 2-way banks)
  u16* Bls = (u16*)(smem + 10240);   // 128 x 40
  if (threadIdx.x == 0) sflag = *flagp;
  __syncthreads();
  const int f32 = sflag;
  const int m0 = blockIdx.x*128, n0 = blockIdx.y*128;
  const int t = threadIdx.x, lane = t & 63, wv = t >> 6;
  const int wm = (wv & 1)*64, wn = (wv >> 1)*64;
  const int lm = lane & 15, lq = lane >> 4;
  f32x4 acc[4][4] = {};
  for (int k0 = 0; k0 < K; k0 += 32) {
    #pragma unroll
    for (int i = 0; i < 2; ++i) {
      int u = t + i*256;
      int row = u >> 2, ch = (u & 3)*8;
      *(uint4*)&Als[row*40 + ch] = *(const uint4*)(A + (size_t)(m0+row)*K + k0 + ch);
      *(uint4*)&Bls[row*40 + ch] = ld8(Bt, (size_t)(n0+row)*K + k0 + ch, f32);
    }
    __syncthreads();
    short8 af[4], bf[4];
    #pragma unroll
    for (int i=0;i<4;++i) af[i] = *(const short8*)&Als[(wm + i*16 + lm)*40 + lq*8];
    #pragma unroll
    for (int i=0;i<4;++i) bf[i] = *(const short8*)&Bls[(wn + i*16 + lm)*40 + lq*8];
    #pragma unroll
    for (int mt=0;mt<4;++mt)
      #pragma unroll
      for (int nt=0;nt<4;++nt)
        acc[mt][nt] = MFMA16(af[mt], bf[nt], acc[mt][nt]);
    __syncthreads();
  }

  if (!shuffle) {
    // 2 chunks of 64 cols; eh = 128 x 72 u16 (18432B, aliases staging)
    u16* eh = (u16*)smem;
    #pragma unroll
    for (int c=0;c<2;++c) {
      __syncthreads();
      if ((wv>>1) == c) {
        #pragma unroll
        for (int nt=0;nt<4;++nt) {
          int col = n0 + c*64 + nt*16 + lm;
          float bv = bias ? ldsc(bias, col, f32) : 0.0f;
          #pragma unroll
          for (int mt=0;mt<4;++mt)
            #pragma unroll
            for (int r=0;r<4;++r) {
              int row = wm + mt*16 + lq*4 + r;
              eh[row*72 + nt*16 + lm] = f2bf(acc[mt][nt][r]*scale + bv);
            }
        }
      }
      __syncthreads();
      {
        int row = t >> 1, off = (t & 1)*32;           // 64B per thread, contiguous
        const uint4* s = (const uint4*)&eh[row*72 + off];
        uint4 v0 = s[0], v1 = s[1], v2 = s[2], v3 = s[3];
        uint4* dp = (uint4*)((u16*)C + (size_t)(m0+row)*N + n0 + c*64 + off);
        dp[0]=v0; dp[1]=v1; dp[2]=v2; dp[3]=v3;
      }
    }
  } else {
    // 4 chunks of 32 cols; ef = 32 output-rows x 136 fp32 (17408B, aliases staging)
    float* ef = (float*)smem;
    const int b = m0 >> 12;
    const int hh0 = (m0 & 4095) >> 6;   // tile = 2 image rows (hh0, hh0+1) x 64 px
    #pragma unroll
    for (int c=0;c<4;++c) {
      __syncthreads();
      if ((wv>>1) == (c>>1)) {
        #pragma unroll
        for (int nt2=0;nt2<2;++nt2) {
          int nt = (c&1)*2 + nt2;
          int col = n0 + wn + nt*16 + lm;             // global col
          float bv = bias ? ldsc(bias, col, f32) : 0.0f;
          int col_rel = nt2*16 + lm;                  // 0..31 within chunk
          int cn_rel = col_rel >> 2, rr = (col_rel >> 1) & 1, ss = col_rel & 1;
          #pragma unroll
          for (int mt=0;mt<4;++mt)
            #pragma unroll
            for (int r=0;r<4;++r) {
              int row = wm + mt*16 + lq*4 + r;        // 0..127 (pixel within tile)
              int orow = cn_rel*4 + (row>>6)*2 + rr;  // output-row within chunk (0..31)
              int ow   = (row & 63)*2 + ss;           // 0..127
              ef[orow*136 + ow] = acc[mt][nt][r]*scale + bv;
            }
        }
      }
      __syncthreads();
      {
        int orow = t >> 3, seg = t & 7;               // 8 lanes cover one full 512B row
        int cn_rel = orow >> 2, oh_rel = orow & 3;
        int cn = ((n0 + c*32) >> 2) + cn_rel;
        size_t obase = (((size_t)(b*256 + cn))*128 + hh0*2 + oh_rel)*128 + seg*16;
        const float4* s = (const float4*)&ef[orow*136 + seg*16];
        float4 v0 = s[0], v1 = s[1], v2 = s[2], v3 = s[3];
        if (f32) {
          float4* dp = (float4*)((float*)C + obase);
          dp[0]=v0; dp[1]=v1; dp[2]=v2; dp[3]=v3;
        } else {
          float vv[16];
          *(float4*)&vv[0]=v0; *(float4*)&vv[4]=v1; *(float4*)&vv[8]=v2; *(float4*)&vv[12]=v3;
          u32 pw[8];
          #pragma unroll
          for (int j=0;j<8;++j) pw[j] = (u32)f2bf(vv[2*j]) | ((u32)f2bf(vv[2*j+1])<<16);
          u16* dp = (u16*)C + obase;
          *(uint4*)dp       = *(uint4*)&pw[0];
          *(uint4*)(dp + 8) = *(uint4*)&pw[4];
        }
      }
    }
  }
}

// ---------------- K2: halo attention, one WG per (block, head) ----------------
#define MASKVAL (-30000.0f)
__global__ __launch_bounds__(256) void k_halo_attn(
  const u16* __restrict__ qo, const u16* __restrict__ kv,
  const void* __restrict__ relh, const void* __restrict__ relw,
  u16* __restrict__ aout, const int* __restrict__ flagp)
{
  __shared__ int sflag;
  __shared__ __align__(16) u16 Qs[64*72];    // Q  [64][72]
  __shared__ __align__(16) u16 KP[128*72];   // K tile; reused: rel tables, then P [64][136]
  __shared__ __align__(16) u16 Vt[64*136];   // V^T tile [64 d][136 keys-padded]
  __shared__ __align__(16) u16 Gw[64*32];    // rel-w logits gather table (bf16)
  __shared__ __align__(16) u16 Gh[64*32];
  if (threadIdx.x == 0) sflag = *flagp;
  __syncthreads();
  const int f32 = sflag;

  const int blk = blockIdx.x, head = blockIdx.y;
  const int bb = blk >> 6, by = (blk >> 3) & 7, bx = blk & 7;
  const int h0 = by*8, w0 = bx*8;
  const int t = threadIdx.x, lane = t & 63, wv = t >> 6;
  const int lm = lane & 15, lq = lane >> 4;
  const size_t pixbase = (size_t)bb * 4096;
  const float LOG2E = 1.4426950408889634f;

  // stage Q (scaled q, 64 rows x 64 d)
  #pragma unroll
  for (int i=0;i<2;++i) {
    int u = t + i*256;
    int row = u >> 3, ch = (u & 7)*8;
    int qx = row >> 3, qy = row & 7;
    size_t p = pixbase + (size_t)(h0+qx)*64 + (w0+qy);
    *(uint4*)&Qs[row*72 + ch] = *(const uint4*)(qo + p*256 + head*64 + ch);
  }
  // stage rel tables (31x64, pad row 31 = 0) into KP region
  {
    u16* RW = KP; u16* RH = KP + 2048;
    if (t < 248) {
      *(uint4*)&RW[t*8] = ld8(relw, (size_t)t*8, f32);
      *(uint4*)&RH[t*8] = ld8(relh, (size_t)t*8, f32);
    } else {
      uint4 z; z.x=z.y=z.z=z.w=0;
      int o = 1984 + (t-248)*8;
      *(uint4*)&RW[o] = z;
      *(uint4*)&RH[o] = z;
    }
  }
  __syncthreads();
  // G = Q @ rel^T (this wave's 16 q-rows, 31 real cols) -> LDS bf16
  {
    const u16* RW = KP; const u16* RH = KP + 2048;
    f32x4 agw[2] = {}, agh[2] = {};
    #pragma unroll
    for (int ks=0;ks<2;++ks) {
      short8 aq = *(const short8*)&Qs[(wv*16 + lm)*72 + ks*32 + lq*8];
      #pragma unroll
      for (int nt=0;nt<2;++nt) {
        short8 bw = *(const short8*)&RW[(nt*16 + lm)*64 + ks*32 + lq*8];
        short8 bh = *(const short8*)&RH[(nt*16 + lm)*64 + ks*32 + lq*8];
        agw[nt] = MFMA16(aq, bw, agw[nt]);
        agh[nt] = MFMA16(aq, bh, agh[nt]);
      }
    }
    #pragma unroll
    for (int nt=0;nt<2;++nt)
      #pragma unroll
      for (int r=0;r<4;++r) {
        int m = wv*16 + lq*4 + r, c = nt*16 + lm;
        Gw[m*32 + c] = f2bf(agw[nt][r]);
        Gh[m*32 + c] = f2bf(agh[nt][r]);
      }
  }
  __syncthreads();   // rel reads done before K staging overwrites KP

  float m_run[4], l_run[4];
  #pragma unroll
  for (int r=0;r<4;++r){ m_run[r] = MASKVAL; l_run[r] = 0.0f; }
  f32x4 acc_o[4] = {};

  for (int tile=0; tile<2; ++tile) {
    // stage K tile (128 keys x 64 d), zero-filled outside the image
    #pragma unroll
    for (int i=0;i<4;++i) {
      int u = t + i*256;
      int kl = u >> 3, ch = (u & 7)*8;
      int ki = tile*8 + (kl >> 4), kj = kl & 15;
      int hk = h0 - 4 + ki, wk = w0 - 4 + kj;
      uint4 v; v.x=v.y=v.z=v.w=0;
      if ((unsigned)hk < 64u && (unsigned)wk < 64u) {
        size_t p = pixbase + (size_t)hk*64 + wk;
        v = *(const uint4*)(kv + p*512 + head*64 + ch);
      }
      *(uint4*)&KP[kl*72 + ch] = v;
    }
    // stage V tile transposed: Vt[d][key]
    {
      int kl = t & 127, db = (t >> 7)*32;
      int ki = tile*8 + (kl >> 4), kj = kl & 15;
      int hk = h0 - 4 + ki, wk = w0 - 4 + kj;
      bool ok = ((unsigned)hk < 64u) && ((unsigned)wk < 64u);
      size_t p = pixbase + (size_t)hk*64 + wk;
      const u16* vp = kv + p*512 + 256 + head*64 + db;
      #pragma unroll
      for (int c=0;c<4;++c) {
        union { uint4 v; u16 s[8]; } uu;
        uu.v.x=uu.v.y=uu.v.z=uu.v.w=0;
        if (ok) uu.v = *(const uint4*)(vp + c*8);
        #pragma unroll
        for (int jj=0;jj<8;++jj) Vt[(db + c*8 + jj)*136 + kl] = uu.s[jj];
      }
    }
    __syncthreads();
    // sim: wave's 16 q-rows x 128 keys
    f32x4 as[8] = {};
    #pragma unroll
    for (int ks=0;ks<2;++ks) {
      short8 aq = *(const short8*)&Qs[(wv*16 + lm)*72 + ks*32 + lq*8];
      #pragma unroll
      for (int nt=0;nt<8;++nt) {
        short8 bk = *(const short8*)&KP[(nt*16 + lm)*72 + ks*32 + lq*8];
        as[nt] = MFMA16(aq, bk, as[nt]);
      }
    }
    __syncthreads();   // every wave done reading K before P overwrites KP
    // online softmax + write P (bf16) into KP as [64][136]
    #pragma unroll
    for (int r=0;r<4;++r) {
      int m = wv*16 + lq*4 + r;
      int qx = m >> 3, qy = m & 7;
      float vals[8]; float rowmax = MASKVAL;
      #pragma unroll
      for (int nt=0;nt<8;++nt) {
        int ki = tile*8 + nt;
        int hk = h0 - 4 + ki, wk = w0 - 4 + lm;
        float v = as[nt][r]
                + bf2f(Gw[m*32 + (lm - qy + 15)])
                + bf2f(Gh[m*32 + (ki - qx + 15)]);
        if (!((unsigned)hk < 64u && (unsigned)wk < 64u)) v = MASKVAL;
        vals[nt] = v;
        rowmax = fmaxf(rowmax, v);
      }
      #pragma unroll
      for (int s=1;s<16;s<<=1) rowmax = fmaxf(rowmax, __shfl_xor(rowmax, s, 64));
      float mnew = fmaxf(m_run[r], rowmax);
      float alpha = exp2f((m_run[r] - mnew)*LOG2E);
      float rs = 0.0f;
      #pragma unroll
      for (int nt=0;nt<8;++nt) {
        float e = exp2f((vals[nt] - mnew)*LOG2E);
        rs += e;
        KP[m*136 + nt*16 + lm] = f2bf(e);
      }
      #pragma unroll
      for (int s=1;s<16;s<<=1) rs += __shfl_xor(rs, s, 64);
      l_run[r] = l_run[r]*alpha + rs;
      m_run[r] = mnew;
      #pragma unroll
      for (int nt=0;nt<4;++nt) acc_o[nt][r] *= alpha;
    }
    __syncthreads();   // P complete
    // O += P @ V
    #pragma unroll
    for (int ks=0;ks<4;++ks) {
      short8 ap = *(const short8*)&KP[(wv*16 + lm)*136 + ks*32 + lq*8];
      #pragma unroll
      for (int nt=0;nt<4;++nt) {
        short8 bv = *(const short8*)&Vt[(nt*16 + lm)*136 + ks*32 + lq*8];
        acc_o[nt] = MFMA16(ap, bv, acc_o[nt]);
      }
    }
    __syncthreads();   // P/V reads done before next tile staging
  }
  // epilogue: normalize and store (pixel-major, col = head*64+dd)
  #pragma unroll
  for (int nt=0;nt<4;++nt)
    #pragma unroll
    for (int r=0;r<4;++r) {
      int m = wv*16 + lq*4 + r;
      int qx = m >> 3, qy = m & 7;
      size_t p = pixbase + (size_t)(h0+qx)*64 + (w0+qy);
      aout[p*256 + head*64 + nt*16 + lm] = f2bf(acc_o[nt][r]/l_run[r]);
    }
}

extern "C" void kernel_launch(void* const* d_in, const int* in_sizes, int n_in,
                              void* d_out, int out_size, void* d_ws, size_t ws_size,
                              hipStream_t stream)
{
  const void* x     = d_in[0];
  const void* wq    = d_in[1];
  const void* wkv   = d_in[2];
  const void* wo    = d_in[3];
  const void* bo    = d_in[4];
  const void* relh  = d_in[5];
  const void* relw  = d_in[6];
  const void* wconv = d_in[7];
  const void* bconv = d_in[8];

  int* flag = (int*)d_ws;
  u16* y2   = (u16*)((char*)d_ws + 4096);     // 32768 x 256 (16 MiB)
  u16* base = (u16*)d_out;
  u16* kvb  = base;                            // 32768 x 512
  u16* qo   = base + 16777216;                 // 32768 x 256
  u16* xt   = base + 25165824;                 // 32768 x 256
  u16* aout = qo;                              // in-place (one WG owns each region)

  k_detect<<<1, 256, 0, stream>>>((const u32*)x, flag);
  k_transpose<<<dim3(64,4,8), 256, 0, stream>>>(x, xt, flag);
  k_gemm_bt<<<dim3(256,2), 256, 0, stream>>>(xt, wq,  nullptr, qo,  32768, 256, 256, 0.125f, 0, flag);
  k_gemm_bt<<<dim3(256,4), 256, 0, stream>>>(xt, wkv, nullptr, kvb, 32768, 512, 256, 1.0f,   0, flag);
  k_halo_attn<<<dim3(512,4), 256, 0, stream>>>(qo, kvb, relh, relw, aout, flag);
  k_gemm_bt<<<dim3(256,2), 256, 0, stream>>>(aout, wo, bo, y2, 32768, 256, 256, 1.0f, 0, flag);
  k_gemm_bt<<<dim3(256,8), 256, 0, stream>>>(y2, wconv, bconv, d_out, 32768, 1024, 256, 1.0f, 1, flag);
}